// Round 6
// baseline (131.645 us; speedup 1.0000x reference)
//
#include <hip/hip_runtime.h>
#include <hip/hip_bf16.h>

#define N_HALF 4096
#define M_TOT  8192
#define K_DIM  256
#define NTILE  2080    // triangle tiles over 64x64 grid of 128-tiles

// ws layout (bytes)
#define WS_SQ      0                       // 8192 f32 (32 KB)
#define WS_COLPART 32768                   // 256*256 f32 (256 KB)
#define WS_SQD     294912                  // 256 f64 (2 KB)
#define WS_BAND    296960                  // f64
#define WS_CNT     296968                  // u32 (k_mmd completion)
#define WS_PCNT    296972                  // u32 (k_pack completion)
#define WS_PARTS   297024                  // 2080 f64 (16640 B)
#define WS_P       313856                  // 8192*256 bf16 = 4 MB

typedef __attribute__((ext_vector_type(8))) short short8;
typedef __attribute__((ext_vector_type(4))) float f32x4;

// ---- pack bf16 + row sumsq + col partial sums + (last block) bandwidth ----
__global__ __launch_bounds__(256) void k_pack(const float* __restrict__ src,
        const float* __restrict__ tgt, ushort* __restrict__ P,
        float* __restrict__ sq, float* __restrict__ colpart,
        double* __restrict__ sqd, double* __restrict__ band,
        unsigned int* __restrict__ pcnt) {
    __shared__ float  colred[4][256];
    __shared__ double sblk[4];
    __shared__ double dred[256];
    __shared__ int    lastf;
    int tid = threadIdx.x, w = tid >> 6, l = tid & 63;
    int blk = blockIdx.x;
    float c0 = 0.f, c1 = 0.f, c2 = 0.f, c3 = 0.f;
    double sacc = 0.0;
#pragma unroll
    for (int j = 0; j < 8; ++j) {
        int row = (blk << 5) + (j << 2) + w;
        const float* base = (row < N_HALF) ? src + (size_t)row * K_DIM
                                           : tgt + (size_t)(row - N_HALF) * K_DIM;
        float4 v = *(const float4*)(base + (l << 2));
        __hip_bfloat16 b0 = __float2bfloat16(v.x), b1 = __float2bfloat16(v.y),
                       b2 = __float2bfloat16(v.z), b3 = __float2bfloat16(v.w);
        ushort4 hv = { *(ushort*)&b0, *(ushort*)&b1, *(ushort*)&b2, *(ushort*)&b3 };
        *(ushort4*)(P + (size_t)row * K_DIM + (l << 2)) = hv;
        float s = v.x * v.x + v.y * v.y + v.z * v.z + v.w * v.w;
#pragma unroll
        for (int off = 32; off > 0; off >>= 1) s += __shfl_down(s, off, 64);
        if (l == 0) { sq[row] = s; sacc += (double)s; }
        c0 += v.x; c1 += v.y; c2 += v.z; c3 += v.w;
    }
    *(float4*)&colred[w][l << 2] = make_float4(c0, c1, c2, c3);
    if (l == 0) sblk[w] = sacc;
    __syncthreads();
    colpart[(blk << 8) + tid] = colred[0][tid] + colred[1][tid] +
                                colred[2][tid] + colred[3][tid];
    if (tid == 0) {
        sqd[blk] = sblk[0] + sblk[1] + sblk[2] + sblk[3];
        __threadfence();
        unsigned int o = atomicAdd(pcnt, 1u);
        lastf = (o == 255u);
    }
    __syncthreads();
    if (lastf) {                       // folded k_stats (block-uniform branch)
        __threadfence();
        dred[tid] = sqd[tid];
        __syncthreads();
        for (int off = 128; off > 0; off >>= 1) {
            if (tid < off) dred[tid] += dred[tid + off];
            __syncthreads();
        }
        double Stot = dred[0];
        __syncthreads();
        double cs = 0.0;
        for (int b = 0; b < 256; ++b) cs += (double)colpart[(b << 8) + tid];
        dred[tid] = cs * cs;
        __syncthreads();
        for (int off = 128; off > 0; off >>= 1) {
            if (tid < off) dred[tid] += dred[tid + off];
            __syncthreads();
        }
        if (tid == 0) {
            double sum_d2 = 2.0 * (double)M_TOT * Stot - 2.0 * dred[0];
            double bw = sum_d2 / ((double)M_TOT * (double)M_TOT - (double)M_TOT);
            *band = bw * 0.25;
        }
    }
}

// ---- register-direct MFMA: fragments straight from L2, no LDS, no barriers ----
// 128x128 tile, 256 thr (4 waves 2x2, wave-tile 64x64), K=256 = 8 kk-steps.
__global__ __launch_bounds__(256, 2) void k_mmd(const ushort* __restrict__ P,
        const float* __restrict__ sq, const double* __restrict__ band,
        double* __restrict__ parts, unsigned int* __restrict__ cnt,
        float* __restrict__ out) {
    __shared__ float  wpart[4];
    __shared__ int    lastf;
    __shared__ double dredm[256];

    // XCD-aware swizzle (2080 = 8 * 260, bijective)
    int raw = blockIdx.x;
    int t = (raw & 7) * 260 + (raw >> 3);
    // triangle decode: t -> (bi, bj), bi <= bj over 64x64 tile grid
    int bi = (int)(64.5 - sqrt(64.5 * 64.5 - 2.0 * (double)t));
    while (bi * 64 - bi * (bi - 1) / 2 > t) --bi;
    while ((bi + 1) * 64 - (bi + 1) * bi / 2 <= t) ++bi;
    int bj = bi + (t - (bi * 64 - bi * (bi - 1) / 2));

    int tid = threadIdx.x, lane = tid & 63, w = tid >> 6;
    int wr = w >> 1, wc = w & 1;
    int row0 = bi << 7, col0 = bj << 7;

    // per-lane fragment bases: row (lane&15), k-chunk (lane>>4)*8
    const ushort* Abase = P + (size_t)(row0 + (wr << 6) + (lane & 15)) * K_DIM
                            + ((lane >> 4) << 3);
    const ushort* Bbase = P + (size_t)(col0 + (wc << 6) + (lane & 15)) * K_DIM
                            + ((lane >> 4) << 3);

    f32x4 accm[4][4] = {};

#pragma unroll
    for (int kk = 0; kk < 8; ++kk) {
        short8 af[4], bf[4];
#pragma unroll
        for (int m = 0; m < 4; ++m)
            af[m] = *(const short8*)(Abase + (m << 12) + (kk << 5));
#pragma unroll
        for (int n = 0; n < 4; ++n)
            bf[n] = *(const short8*)(Bbase + (n << 12) + (kk << 5));
#pragma unroll
        for (int m = 0; m < 4; ++m)
#pragma unroll
            for (int n = 0; n < 4; ++n)
                accm[m][n] = __builtin_amdgcn_mfma_f32_16x16x32_bf16(
                    af[m], bf[n], accm[m][n], 0, 0, 0);
    }

    // ---- epilogue: q = -d2*E16; t4=exp2(q); squarings give all 5 terms ----
    bool isdiag = (bi == bj);
    double bwd = *band;
    float E16 = (float)(1.4426950408889634 / (bwd * 16.0));
    float twoE16 = 2.f * E16;

    float A4[4][4];
#pragma unroll
    for (int m = 0; m < 4; ++m) {
        float4 v = *(const float4*)&sq[row0 + (wr << 6) + (m << 4) + ((lane >> 4) << 2)];
        A4[m][0] = -v.x * E16; A4[m][1] = -v.y * E16;
        A4[m][2] = -v.z * E16; A4[m][3] = -v.w * E16;
    }
    float Bv[4];
#pragma unroll
    for (int n = 0; n < 4; ++n)
        Bv[n] = -sq[col0 + (wc << 6) + (n << 4) + (lane & 15)] * E16;

    float p0 = 0.f, p1 = 0.f, p2 = 0.f, p3 = 0.f, p4 = 0.f;
#pragma unroll
    for (int m = 0; m < 4; ++m)
#pragma unroll
    for (int n = 0; n < 4; ++n) {
        int rlb = (wr << 6) + (m << 4) + ((lane >> 4) << 2);
        int cl  = (wc << 6) + (n << 4) + (lane & 15);
#pragma unroll
        for (int j = 0; j < 4; ++j) {
            float q = fmaf(accm[m][n][j], twoE16, A4[m][j] + Bv[n]);
            if (isdiag && (rlb + j == cl)) q = 0.f;   // exact-zero diagonal
            float t4 = exp2f(q);
            float t3 = t4 * t4, t2 = t3 * t3, t1 = t2 * t2, t0 = t1 * t1;
            p4 += t4; p3 += t3; p2 += t2; p1 += t1; p0 += t0;
        }
    }
    float part = (p0 + p1) + (p2 + p3) + p4;
#pragma unroll
    for (int off = 32; off > 0; off >>= 1) part += __shfl_down(part, off, 64);

    if (lane == 0) wpart[w] = part;
    __syncthreads();
    if (tid == 0) {
        float sgn = ((row0 < N_HALF) == (col0 < N_HALF)) ? 1.f : -1.f;
        float wt  = isdiag ? 1.f : 2.f;
        double tot = (double)wpart[0] + (double)wpart[1] +
                     (double)wpart[2] + (double)wpart[3];
        parts[raw] = tot * (double)(sgn * wt);
        __threadfence();
        unsigned int o = atomicAdd(cnt, 1u);
        lastf = (o == NTILE - 1u);
    }
    __syncthreads();
    if (lastf) {                      // last block: reduce all partials
        __threadfence();
        double s = 0.0;
        for (int i = tid; i < NTILE; i += 256) s += parts[i];
        dredm[tid] = s;
        __syncthreads();
        for (int off = 128; off > 0; off >>= 1) {
            if (tid < off) dredm[tid] += dredm[tid + off];
            __syncthreads();
        }
        if (tid == 0)
            out[0] = (float)(dredm[0] * (1.0 / ((double)N_HALF * (double)N_HALF)));
    }
}

extern "C" void kernel_launch(void* const* d_in, const int* in_sizes, int n_in,
                              void* d_out, int out_size, void* d_ws, size_t ws_size,
                              hipStream_t stream) {
    const float* src = (const float*)d_in[0];
    const float* tgt = (const float*)d_in[1];
    float*  sq      = (float*)((char*)d_ws + WS_SQ);
    float*  colpart = (float*)((char*)d_ws + WS_COLPART);
    double* sqd     = (double*)((char*)d_ws + WS_SQD);
    double* band    = (double*)((char*)d_ws + WS_BAND);
    unsigned int* cnt  = (unsigned int*)((char*)d_ws + WS_CNT);
    unsigned int* pcnt = (unsigned int*)((char*)d_ws + WS_PCNT);
    double* parts   = (double*)((char*)d_ws + WS_PARTS);
    ushort* P       = (ushort*)((char*)d_ws + WS_P);

    hipMemsetAsync((char*)d_ws + WS_BAND, 0, 64, stream);
    k_pack <<<256,   256, 0, stream>>>(src, tgt, P, sq, colpart, sqd, band, pcnt);
    k_mmd  <<<NTILE, 256, 0, stream>>>(P, sq, band, parts, cnt, (float*)d_out);
}

// Round 8
// 97.570 us; speedup vs baseline: 1.3492x; 1.3492x over previous
//
#include <hip/hip_runtime.h>
#include <hip/hip_bf16.h>

#define N_HALF 4096
#define M_TOT  8192
#define K_DIM  256
#define NTILE  528     // triangle tiles over 32x32 grid of 256-tiles

// ws layout (bytes)
#define WS_SQ      0                       // 8192 f32 (32 KB)
#define WS_COLPART 32768                   // 512*256 f32 (512 KB)
#define WS_SQD     557056                  // 512 f64 (4 KB)
#define WS_BAND    561152                  // f64
#define WS_CNT     561160                  // u32 (k_mmd completion)
#define WS_PCNT    561164                  // u32 (k_pack completion)
#define WS_PARTS   561216                  // 528 f64 (4224 B)
#define WS_P       565504                  // 8192*256 bf16 = 4 MB

typedef __attribute__((ext_vector_type(8)))  short short8;
typedef __attribute__((ext_vector_type(16))) float f32x16;

__device__ __forceinline__ void gload16(const void* g, void* l) {
    __builtin_amdgcn_global_load_lds(
        (const __attribute__((address_space(1))) void*)g,
        (__attribute__((address_space(3))) void*)l, 16, 0, 0);
}

__device__ __forceinline__ float rexp2(float x) {   // inputs in [-1,0]: raw op safe
    float r; asm("v_exp_f32 %0, %1" : "=v"(r) : "v"(x)); return r;
}

// ---- pack bf16 + row sumsq + col partial sums + (last block) bandwidth ----
__global__ __launch_bounds__(256) void k_pack(const float* __restrict__ src,
        const float* __restrict__ tgt, ushort* __restrict__ P,
        float* __restrict__ sq, float* __restrict__ colpart,
        double* __restrict__ sqd, double* __restrict__ band,
        unsigned int* __restrict__ pcnt) {
    __shared__ float  colred[4][256];
    __shared__ double sblk[4];
    __shared__ double dred[256];
    __shared__ int    lastf;
    int tid = threadIdx.x, w = tid >> 6, l = tid & 63;
    int blk = blockIdx.x;
    float c0 = 0.f, c1 = 0.f, c2 = 0.f, c3 = 0.f;
    double sacc = 0.0;
#pragma unroll
    for (int j = 0; j < 4; ++j) {
        int row = (blk << 4) + (j << 2) + w;
        const float* base = (row < N_HALF) ? src + (size_t)row * K_DIM
                                           : tgt + (size_t)(row - N_HALF) * K_DIM;
        float4 v = *(const float4*)(base + (l << 2));
        __hip_bfloat16 b0 = __float2bfloat16(v.x), b1 = __float2bfloat16(v.y),
                       b2 = __float2bfloat16(v.z), b3 = __float2bfloat16(v.w);
        ushort4 hv = { *(ushort*)&b0, *(ushort*)&b1, *(ushort*)&b2, *(ushort*)&b3 };
        *(ushort4*)(P + (size_t)row * K_DIM + (l << 2)) = hv;
        float s = v.x * v.x + v.y * v.y + v.z * v.z + v.w * v.w;
#pragma unroll
        for (int off = 32; off > 0; off >>= 1) s += __shfl_down(s, off, 64);
        if (l == 0) { sq[row] = s; sacc += (double)s; }
        c0 += v.x; c1 += v.y; c2 += v.z; c3 += v.w;
    }
    *(float4*)&colred[w][l << 2] = make_float4(c0, c1, c2, c3);
    if (l == 0) sblk[w] = sacc;
    __syncthreads();
    colpart[(blk << 8) + tid] = colred[0][tid] + colred[1][tid] +
                                colred[2][tid] + colred[3][tid];
    if (tid == 0) {
        sqd[blk] = sblk[0] + sblk[1] + sblk[2] + sblk[3];
        __threadfence();
        unsigned int o = atomicAdd(pcnt, 1u);
        lastf = (o == 511u);
    }
    __syncthreads();
    if (lastf) {                       // folded bandwidth computation
        __threadfence();
        dred[tid] = sqd[tid] + sqd[tid + 256];
        __syncthreads();
        for (int off = 128; off > 0; off >>= 1) {
            if (tid < off) dred[tid] += dred[tid + off];
            __syncthreads();
        }
        double Stot = dred[0];
        __syncthreads();
        double cs = 0.0;
#pragma unroll 16
        for (int b = 0; b < 512; ++b) cs += (double)colpart[(b << 8) + tid];
        dred[tid] = cs * cs;
        __syncthreads();
        for (int off = 128; off > 0; off >>= 1) {
            if (tid < off) dred[tid] += dred[tid + off];
            __syncthreads();
        }
        if (tid == 0) {
            double sum_d2 = 2.0 * (double)M_TOT * Stot - 2.0 * dred[0];
            double bw = sum_d2 / ((double)M_TOT * (double)M_TOT - (double)M_TOT);
            *band = bw * 0.25;
        }
    }
}

// ---- epilogue helper: d2 -> 5 gaussians (exp2 + squarings), signed part ----
template<bool DIAG>
__device__ __forceinline__ float epi_sum(const f32x16 (&acc)[4][2],
        const float* __restrict__ sq, int row0, int col0,
        int wr, int wc, int l31, int l5, float E16, float twoE16) {
    float Bv[2];
#pragma unroll
    for (int nt = 0; nt < 2; ++nt)
        Bv[nt] = -sq[col0 + (wc << 6) + (nt << 5) + l31] * E16;
    float p0 = 0.f, p1 = 0.f, p2 = 0.f, p3 = 0.f, p4 = 0.f;
#pragma unroll
    for (int mt = 0; mt < 4; ++mt) {
        int rb = row0 + (wr << 7) + (mt << 5) + (l5 << 2);
        float4 sv[4];
#pragma unroll
        for (int q = 0; q < 4; ++q) sv[q] = *(const float4*)&sq[rb + (q << 3)];
        float A16[16];
#pragma unroll
        for (int q = 0; q < 4; ++q) {
            A16[(q << 2) + 0] = -sv[q].x * E16;
            A16[(q << 2) + 1] = -sv[q].y * E16;
            A16[(q << 2) + 2] = -sv[q].z * E16;
            A16[(q << 2) + 3] = -sv[q].w * E16;
        }
#pragma unroll
        for (int nt = 0; nt < 2; ++nt) {
            float bvn = Bv[nt];
#pragma unroll
            for (int reg = 0; reg < 16; ++reg) {
                float qq = fmaf(acc[mt][nt][reg], twoE16, A16[reg] + bvn);
                if (DIAG) {
                    int rl  = (wr << 7) + (mt << 5) + (l5 << 2) +
                              (reg & 3) + ((reg >> 2) << 3);
                    int cll = (wc << 6) + (nt << 5) + l31;
                    if (rl == cll) qq = 0.f;    // exact-zero diagonal
                }
                float t4 = rexp2(qq);
                float t3 = t4 * t4, t2 = t3 * t3, t1 = t2 * t2, t0 = t1 * t1;
                p4 += t4; p3 += t3; p2 += t2; p1 += t1; p0 += t0;
            }
        }
    }
    return (p0 + p1) + (p2 + p3) + p4;
}

// ---- fused MFMA 256x256 tile, 8 waves (2x4), 32x32x16 bf16, BK=64 dbuf ----
__global__ __launch_bounds__(512, 2) void k_mmd(const ushort* __restrict__ P,
        const float* __restrict__ sq, const double* __restrict__ band,
        double* __restrict__ parts, unsigned int* __restrict__ cnt,
        float* __restrict__ out) {
    __shared__ ushort As[2][256][64];
    __shared__ ushort Bs[2][256][64];

    // XCD-aware swizzle (528 = 8 * 66, bijective)
    int raw = blockIdx.x;
    int t = (raw & 7) * 66 + (raw >> 3);
    // triangle decode over 32x32 grid
    int bi = (int)(32.5 - sqrt(32.5 * 32.5 - 2.0 * (double)t));
    while (bi * 32 - bi * (bi - 1) / 2 > t) --bi;
    while ((bi + 1) * 32 - (bi + 1) * bi / 2 <= t) ++bi;
    int bj = bi + (t - (bi * 32 - bi * (bi - 1) / 2));

    int tid = threadIdx.x, lane = tid & 63, w = tid >> 6;
    int wr = w >> 2, wc = w & 3;            // 2 x 4 wave grid, wave-tile 128x64
    int row0 = bi << 8, col0 = bj << 8;
    const ushort* Pa = P + (size_t)row0 * K_DIM;
    const ushort* Pb = P + (size_t)col0 * K_DIM;

    int l31 = lane & 31, l5 = lane >> 5, l7 = lane & 7;

    // fragment LDS byte offsets (row-major [256][64] ushort, 128 B rows);
    // logical 16B chunk c stored at c ^ (row&7); row&7 == lane&7 here.
    int aoff[4], boff[2], cxb[4];
#pragma unroll
    for (int mt = 0; mt < 4; ++mt)
        aoff[mt] = ((wr << 7) + (mt << 5) + l31) << 7;
#pragma unroll
    for (int nt = 0; nt < 2; ++nt)
        boff[nt] = ((wc << 6) + (nt << 5) + l31) << 7;
#pragma unroll
    for (int kk = 0; kk < 4; ++kk)
        cxb[kk] = (((kk << 1) + l5) ^ l7) << 4;

    // staging: rows (p*64 + tid>>3), swizzled source chunk, linear LDS dest
    int ssc = (tid & 7) ^ ((tid >> 3) & 7);
    size_t soff = (size_t)(tid >> 3) * K_DIM + (ssc << 3);
    int ldst = tid << 4;

    f32x16 acc[4][2] = {};

#define STAGE(buf, kc)                                                        \
    _Pragma("unroll")                                                         \
    for (int p = 0; p < 4; ++p) {                                             \
        gload16(Pa + soff + ((size_t)(p << 6) * K_DIM) + (kc),                \
                (char*)&As[buf][0][0] + (p << 13) + ldst);                    \
        gload16(Pb + soff + ((size_t)(p << 6) * K_DIM) + (kc),                \
                (char*)&Bs[buf][0][0] + (p << 13) + ldst);                    \
    }

    STAGE(0, 0)
    __syncthreads();   // vmcnt(0): buf0 resident

#pragma unroll
    for (int it = 0; it < 4; ++it) {
        int cur = it & 1;
        if (it < 3) { STAGE(cur ^ 1, (it + 1) << 6) }   // overlap next stage
        const char* Ab = (const char*)&As[cur][0][0];
        const char* Bb = (const char*)&Bs[cur][0][0];
#pragma unroll
        for (int kk = 0; kk < 4; ++kk) {
            short8 af[4], bf[2];
#pragma unroll
            for (int mt = 0; mt < 4; ++mt)
                af[mt] = *(const short8*)(Ab + aoff[mt] + cxb[kk]);
#pragma unroll
            for (int nt = 0; nt < 2; ++nt)
                bf[nt] = *(const short8*)(Bb + boff[nt] + cxb[kk]);
#pragma unroll
            for (int mt = 0; mt < 4; ++mt)
#pragma unroll
                for (int nt = 0; nt < 2; ++nt)
                    acc[mt][nt] = __builtin_amdgcn_mfma_f32_32x32x16_bf16(
                        af[mt], bf[nt], acc[mt][nt], 0, 0, 0);
        }
        __syncthreads();   // drains staged loads; WAR-protects buffer reuse
    }

    // ---- epilogue ----
    bool isdiag = (bi == bj);
    double bwd = *band;
    float E16 = (float)(1.4426950408889634 / (bwd * 16.0));
    float twoE16 = 2.f * E16;

    float part = isdiag
        ? epi_sum<true >(acc, sq, row0, col0, wr, wc, l31, l5, E16, twoE16)
        : epi_sum<false>(acc, sq, row0, col0, wr, wc, l31, l5, E16, twoE16);
#pragma unroll
    for (int off = 32; off > 0; off >>= 1) part += __shfl_down(part, off, 64);

    // LDS dead: reuse As for wpart/flag, Bs for f64 reduce
    float*  wpart = (float*)&As[0][0][0];
    int*    lastf = (int*)(wpart + 16);
    double* dredm = (double*)&Bs[0][0][0];

    if (lane == 0) wpart[w] = part;
    __syncthreads();
    if (tid == 0) {
        float sgn = ((row0 < N_HALF) == (col0 < N_HALF)) ? 1.f : -1.f;
        float wt  = isdiag ? 1.f : 2.f;
        double tot = 0.0;
#pragma unroll
        for (int i = 0; i < 8; ++i) tot += (double)wpart[i];
        parts[raw] = tot * (double)(sgn * wt);
        __threadfence();
        unsigned int o = atomicAdd(cnt, 1u);
        *lastf = (o == NTILE - 1u);
    }
    __syncthreads();
    if (*lastf) {                      // last block: reduce all partials
        __threadfence();
        double s = 0.0;
        for (int i = tid; i < NTILE; i += 512) s += parts[i];
        dredm[tid] = s;
        __syncthreads();
        for (int off = 256; off > 0; off >>= 1) {
            if (tid < off) dredm[tid] += dredm[tid + off];
            __syncthreads();
        }
        if (tid == 0)
            out[0] = (float)(dredm[0] * (1.0 / ((double)N_HALF * (double)N_HALF)));
    }
}

extern "C" void kernel_launch(void* const* d_in, const int* in_sizes, int n_in,
                              void* d_out, int out_size, void* d_ws, size_t ws_size,
                              hipStream_t stream) {
    const float* src = (const float*)d_in[0];
    const float* tgt = (const float*)d_in[1];
    float*  sq      = (float*)((char*)d_ws + WS_SQ);
    float*  colpart = (float*)((char*)d_ws + WS_COLPART);
    double* sqd     = (double*)((char*)d_ws + WS_SQD);
    double* band    = (double*)((char*)d_ws + WS_BAND);
    unsigned int* cnt  = (unsigned int*)((char*)d_ws + WS_CNT);
    unsigned int* pcnt = (unsigned int*)((char*)d_ws + WS_PCNT);
    double* parts   = (double*)((char*)d_ws + WS_PARTS);
    ushort* P       = (ushort*)((char*)d_ws + WS_P);

    hipMemsetAsync((char*)d_ws + WS_BAND, 0, 64, stream);
    k_pack <<<512,   256, 0, stream>>>(src, tgt, P, sq, colpart, sqd, band, pcnt);
    k_mmd  <<<NTILE, 512, 0, stream>>>(P, sq, band, parts, cnt, (float*)d_out);
}

// Round 10
// 80.119 us; speedup vs baseline: 1.6431x; 1.2178x over previous
//
#include <hip/hip_runtime.h>
#include <hip/hip_bf16.h>

#define N_HALF 4096
#define M_TOT  8192
#define K_DIM  256
#define NTILE  528     // triangle tiles over 32x32 grid of 256-tiles

// ws layout (bytes)
#define WS_SQ      0                       // 8192 f32 (32 KB)
#define WS_COLPART 32768                   // 128*256 f32 (128 KB)
#define WS_SQD     163840                  // 128 f64 (1 KB)
#define WS_BAND    164864                  // f64
#define WS_CNT     164872                  // u32 (k_mmd completion)
#define WS_PCNT    164876                  // u32 (k_pack completion)
#define WS_PARTS   164928                  // 528 f64 (4224 B)
#define WS_P       169216                  // 8192*256 bf16 = 4 MB

typedef __attribute__((ext_vector_type(8))) short short8;
typedef __attribute__((ext_vector_type(4))) float f32x4;

__device__ __forceinline__ void gload16(const void* g, void* l) {
    __builtin_amdgcn_global_load_lds(
        (const __attribute__((address_space(1))) void*)g,
        (__attribute__((address_space(3))) void*)l, 16, 0, 0);
}

__device__ __forceinline__ float rexp2(float x) {   // q in [-1,0]: raw op safe
    float r; asm("v_exp_f32 %0, %1" : "=v"(r) : "v"(x)); return r;
}

#define SB0   __builtin_amdgcn_sched_barrier(0)
#define BAR   __builtin_amdgcn_s_barrier()
#define VMC8  asm volatile("s_waitcnt vmcnt(8)" ::: "memory")
#define VMC0  asm volatile("s_waitcnt vmcnt(0)" ::: "memory")
#define LGKM0 asm volatile("s_waitcnt lgkmcnt(0)" ::: "memory")

// ---- pack bf16 + row sumsq + col partial sums + (last block) bandwidth ----
__global__ __launch_bounds__(256) void k_pack(const float* __restrict__ src,
        const float* __restrict__ tgt, ushort* __restrict__ P,
        float* __restrict__ sq, float* __restrict__ colpart,
        double* __restrict__ sqd, double* __restrict__ band,
        unsigned int* __restrict__ pcnt) {
    __shared__ float  colred[4][256];
    __shared__ double sblk[4];
    __shared__ double dred[256];
    __shared__ int    lastf;
    int tid = threadIdx.x, w = tid >> 6, l = tid & 63;
    int blk = blockIdx.x;                       // 128 blocks x 64 rows
    float c0 = 0.f, c1 = 0.f, c2 = 0.f, c3 = 0.f;
    double sacc = 0.0;
#pragma unroll
    for (int j = 0; j < 16; ++j) {
        int row = (blk << 6) + (j << 2) + w;
        const float* base = (row < N_HALF) ? src + (size_t)row * K_DIM
                                           : tgt + (size_t)(row - N_HALF) * K_DIM;
        float4 v = *(const float4*)(base + (l << 2));
        __hip_bfloat16 b0 = __float2bfloat16(v.x), b1 = __float2bfloat16(v.y),
                       b2 = __float2bfloat16(v.z), b3 = __float2bfloat16(v.w);
        ushort4 hv = { *(ushort*)&b0, *(ushort*)&b1, *(ushort*)&b2, *(ushort*)&b3 };
        *(ushort4*)(P + (size_t)row * K_DIM + (l << 2)) = hv;
        float s = v.x * v.x + v.y * v.y + v.z * v.z + v.w * v.w;
#pragma unroll
        for (int off = 32; off > 0; off >>= 1) s += __shfl_down(s, off, 64);
        if (l == 0) { sq[row] = s; sacc += (double)s; }
        c0 += v.x; c1 += v.y; c2 += v.z; c3 += v.w;
    }
    *(float4*)&colred[w][l << 2] = make_float4(c0, c1, c2, c3);
    if (l == 0) sblk[w] = sacc;
    __syncthreads();
    colpart[(blk << 8) + tid] = colred[0][tid] + colred[1][tid] +
                                colred[2][tid] + colred[3][tid];
    if (tid == 0) {
        sqd[blk] = sblk[0] + sblk[1] + sblk[2] + sblk[3];
        __threadfence();
        unsigned int o = atomicAdd(pcnt, 1u);
        lastf = (o == 127u);
    }
    __syncthreads();
    if (lastf) {                       // folded bandwidth computation
        __threadfence();
        dred[tid] = (tid < 128) ? sqd[tid] : 0.0;
        __syncthreads();
        for (int off = 128; off > 0; off >>= 1) {
            if (tid < off) dred[tid] += dred[tid + off];
            __syncthreads();
        }
        double Stot = dred[0];
        __syncthreads();
        double cs = 0.0;
#pragma unroll 16
        for (int b = 0; b < 128; ++b) cs += (double)colpart[(b << 8) + tid];
        dred[tid] = cs * cs;
        __syncthreads();
        for (int off = 128; off > 0; off >>= 1) {
            if (tid < off) dred[tid] += dred[tid + off];
            __syncthreads();
        }
        if (tid == 0) {
            double sum_d2 = 2.0 * (double)M_TOT * Stot - 2.0 * dred[0];
            double bw = sum_d2 / ((double)M_TOT * (double)M_TOT - (double)M_TOT);
            *band = bw * 0.25;
        }
    }
}

// stage one 256x64 panel (32 KB): 4 gload16 per thread
__device__ __forceinline__ void stagePanel(const ushort* srcbase, size_t soff,
                                           char* ldsbase, int ldst) {
#pragma unroll
    for (int p = 0; p < 4; ++p)
        gload16(srcbase + soff + ((size_t)(p << 6) * K_DIM),
                ldsbase + (p << 13) + ldst);
}

// one K-tile of compute: 2 kk sub-phases x (12 ds_read_b128 + 32 MFMA)
__device__ __forceinline__ void computeTile(const ushort (&A)[256][64],
        const ushort (&B)[256][64], const int (&aoff)[8], const int (&boff)[4],
        f32x4 (&acc)[8][4]) {
#pragma unroll
    for (int kk = 0; kk < 2; ++kk) {
        short8 af[8], bf[4];
#pragma unroll
        for (int mt = 0; mt < 8; ++mt)
            af[mt] = *(const short8*)((const char*)&A[0][0] + (aoff[mt] ^ (kk << 6)));
#pragma unroll
        for (int nt = 0; nt < 4; ++nt)
            bf[nt] = *(const short8*)((const char*)&B[0][0] + (boff[nt] ^ (kk << 6)));
        __builtin_amdgcn_s_setprio(1);
#pragma unroll
        for (int mt = 0; mt < 8; ++mt)
#pragma unroll
            for (int nt = 0; nt < 4; ++nt)
                acc[mt][nt] = __builtin_amdgcn_mfma_f32_16x16x32_bf16(
                    af[mt], bf[nt], acc[mt][nt], 0, 0, 0);
        __builtin_amdgcn_s_setprio(0);
    }
}

// ---- fused MFMA 256x256 tile, 8 waves (2x4), 16x16x32, counted-vmcnt dbuf ----
__global__ __launch_bounds__(512, 2) void k_mmd(const ushort* __restrict__ P,
        const float* __restrict__ sq, const double* __restrict__ band,
        double* __restrict__ parts, unsigned int* __restrict__ cnt,
        float* __restrict__ out) {
    __shared__ ushort As[2][256][64];
    __shared__ ushort Bs[2][256][64];

    // XCD-aware swizzle (528 = 8 * 66, bijective)
    int raw = blockIdx.x;
    int t = (raw & 7) * 66 + (raw >> 3);
    // triangle decode over 32x32 grid
    int bi = (int)(32.5 - sqrt(32.5 * 32.5 - 2.0 * (double)t));
    while (bi * 32 - bi * (bi - 1) / 2 > t) --bi;
    while ((bi + 1) * 32 - (bi + 1) * bi / 2 <= t) ++bi;
    int bj = bi + (t - (bi * 32 - bi * (bi - 1) / 2));

    int tid = threadIdx.x, lane = tid & 63, w = tid >> 6;
    int wr = w >> 2, wc = w & 3;            // 2 x 4 wave grid, wave-tile 128x64
    int row0 = bi << 8, col0 = bj << 8;
    const ushort* Pa = P + (size_t)row0 * K_DIM;
    const ushort* Pb = P + (size_t)col0 * K_DIM;

    // fragment LDS byte offsets (rows 128 B; logical chunk c at c ^ (row&7))
    int cx = ((lane >> 4) ^ (lane & 7)) << 4;
    int aoff[8], boff[4];
#pragma unroll
    for (int mt = 0; mt < 8; ++mt)
        aoff[mt] = (((wr << 7) + (mt << 4) + (lane & 15)) << 7) + cx;
#pragma unroll
    for (int nt = 0; nt < 4; ++nt)
        boff[nt] = (((wc << 6) + (nt << 4) + (lane & 15)) << 7) + cx;

    // staging geometry: rows (w*8 + lane>>3) + p*64, inverse-swizzled source
    size_t soff = (size_t)((w << 3) + (lane >> 3)) * K_DIM
                + (((lane & 7) ^ (lane >> 3)) << 3);
    int ldst = tid << 4;

    f32x4 acc[8][4] = {};

    // prologue: tile 0 panels (8 loads in flight)
    stagePanel(Pa, soff, (char*)&As[0][0][0], ldst);
    stagePanel(Pb, soff, (char*)&Bs[0][0][0], ldst);
    // ---- tile 0 ----
    stagePanel(Pa + 64, soff, (char*)&As[1][0][0], ldst);
    stagePanel(Pb + 64, soff, (char*)&Bs[1][0][0], ldst);
    SB0; VMC8; SB0; BAR; SB0;            // tile0 resident on ALL waves
    computeTile(As[0], Bs[0], aoff, boff, acc);
    SB0; LGKM0; SB0; BAR; SB0;           // all waves done reading buf0
    // ---- tile 1 ----
    stagePanel(Pa + 128, soff, (char*)&As[0][0][0], ldst);
    stagePanel(Pb + 128, soff, (char*)&Bs[0][0][0], ldst);
    SB0; VMC8; SB0; BAR; SB0;
    computeTile(As[1], Bs[1], aoff, boff, acc);
    SB0; LGKM0; SB0; BAR; SB0;
    // ---- tile 2 ----
    stagePanel(Pa + 192, soff, (char*)&As[1][0][0], ldst);
    stagePanel(Pb + 192, soff, (char*)&Bs[1][0][0], ldst);
    SB0; VMC8; SB0; BAR; SB0;
    computeTile(As[0], Bs[0], aoff, boff, acc);
    SB0; LGKM0; SB0; BAR; SB0;
    // ---- tile 3 (final; full drain) ----
    SB0; VMC0; SB0; BAR; SB0;
    computeTile(As[1], Bs[1], aoff, boff, acc);

    // ---- epilogue: q = -d2*E16; t4=exp2(q); squarings give all 5 terms ----
    bool isdiag = (bi == bj);
    double bwd = *band;
    float E16 = (float)(1.4426950408889634 / (bwd * 16.0));
    float twoE16 = 2.f * E16;

    float Bv[4];
#pragma unroll
    for (int nt = 0; nt < 4; ++nt)
        Bv[nt] = -sq[col0 + (wc << 6) + (nt << 4) + (lane & 15)] * E16;

    float p0 = 0.f, p1 = 0.f, p2 = 0.f, p3 = 0.f, p4 = 0.f;
#pragma unroll
    for (int mt = 0; mt < 8; ++mt) {
        float4 v = *(const float4*)&sq[row0 + (wr << 7) + (mt << 4) +
                                       ((lane >> 4) << 2)];
        float A4[4] = { -v.x * E16, -v.y * E16, -v.z * E16, -v.w * E16 };
        int rlb = (wr << 7) + (mt << 4) + ((lane >> 4) << 2);
#pragma unroll
        for (int nt = 0; nt < 4; ++nt) {
            int cl = (wc << 6) + (nt << 4) + (lane & 15);
#pragma unroll
            for (int j = 0; j < 4; ++j) {
                float q = fmaf(acc[mt][nt][j], twoE16, A4[j] + Bv[nt]);
                if (isdiag && (rlb + j == cl)) q = 0.f;   // exact-zero diagonal
                float t4 = rexp2(q);
                float t3 = t4 * t4, t2 = t3 * t3, t1 = t2 * t2, t0 = t1 * t1;
                p4 += t4; p3 += t3; p2 += t2; p1 += t1; p0 += t0;
            }
        }
    }
    float part = (p0 + p1) + (p2 + p3) + p4;
#pragma unroll
    for (int off = 32; off > 0; off >>= 1) part += __shfl_down(part, off, 64);

    // LDS dead: reuse As[0] region for wpart/flag, Bs[0] region for f64 reduce
    float*  wpart = (float*)&As[0][0][0];
    int*    lastf = (int*)(wpart + 16);
    double* dredm = (double*)&Bs[0][0][0];

    if (lane == 0) wpart[w] = part;
    __syncthreads();
    if (tid == 0) {
        float sgn = ((row0 < N_HALF) == (col0 < N_HALF)) ? 1.f : -1.f;
        float wt  = isdiag ? 1.f : 2.f;
        double tot = 0.0;
#pragma unroll
        for (int i = 0; i < 8; ++i) tot += (double)wpart[i];
        parts[raw] = tot * (double)(sgn * wt);
        __threadfence();
        unsigned int o = atomicAdd(cnt, 1u);
        *lastf = (o == NTILE - 1u);
    }
    __syncthreads();
    if (*lastf) {                      // last block: reduce all partials
        __threadfence();
        double s = 0.0;
        for (int i = tid; i < NTILE; i += 512) s += parts[i];
        dredm[tid] = s;
        __syncthreads();
        for (int off = 256; off > 0; off >>= 1) {
            if (tid < off) dredm[tid] += dredm[tid + off];
            __syncthreads();
        }
        if (tid == 0)
            out[0] = (float)(dredm[0] * (1.0 / ((double)N_HALF * (double)N_HALF)));
    }
}

extern "C" void kernel_launch(void* const* d_in, const int* in_sizes, int n_in,
                              void* d_out, int out_size, void* d_ws, size_t ws_size,
                              hipStream_t stream) {
    const float* src = (const float*)d_in[0];
    const float* tgt = (const float*)d_in[1];
    float*  sq      = (float*)((char*)d_ws + WS_SQ);
    float*  colpart = (float*)((char*)d_ws + WS_COLPART);
    double* sqd     = (double*)((char*)d_ws + WS_SQD);
    double* band    = (double*)((char*)d_ws + WS_BAND);
    unsigned int* cnt  = (unsigned int*)((char*)d_ws + WS_CNT);
    unsigned int* pcnt = (unsigned int*)((char*)d_ws + WS_PCNT);
    double* parts   = (double*)((char*)d_ws + WS_PARTS);
    ushort* P       = (ushort*)((char*)d_ws + WS_P);

    hipMemsetAsync((char*)d_ws + WS_BAND, 0, 64, stream);
    k_pack <<<128,   256, 0, stream>>>(src, tgt, P, sq, colpart, sqd, band, pcnt);
    k_mmd  <<<NTILE, 512, 0, stream>>>(P, sq, band, parts, cnt, (float*)d_out);
}